// Round 1
// baseline (88.842 us; speedup 1.0000x reference)
//
#include <hip/hip_runtime.h>
#include <math.h>

// Problem constants
#define BB 128
#define ND 32
#define NIJ 16384
#define EPS2 0.25f
#define EPS4 0.0625f

// Tiling: 256 blocks x 64 ij, full batch per block; 512 thr = 64 bl x 8 gij
// Each thread: 2 b (bl, bl+64) x 8 ij (gij + 8*it) -> coef reads amortized 2x
#define TIJ 64
#define NBLK (NIJ / TIJ)        // 256 (1/CU)
#define NTHR 512
#define ROWF 132                // coef row: cA32|cB32|K32|KV32|pad4

// LDS layout (floats)
#define XS_OFF  8448            // X stage [128][36] (2-way banks)
#define CC_OFF  13056
#define LAM_OFF 13120
#define LDS_FL  13184           // 52.7 KB
#define STG_ROW 36

// part layout per block (packed): num[128][32] @0, den[128] @4096
#define PART_STRIDE 4224
#define DEN_OFF_P 4096

__global__ __launch_bounds__(NTHR, 2) void gmm_fused(
    const float* __restrict__ Xg,
    const float* __restrict__ tptr,
    const float* __restrict__ Mu0, const float* __restrict__ Mu1,
    const float* __restrict__ S0,  const float* __restrict__ S1,
    const float* __restrict__ Lam,
    float* __restrict__ part)
{
    __shared__ __align__(16) float lds[LDS_FL];

    const int tid  = threadIdx.x;
    const int blk  = blockIdx.x;
    const int ij0g = blk * TIJ;
    const float t   = tptr[0];
    const float omt = 1.0f - t;

    // ---- Phase 1a: X full batch -> LDS stage [128][36] (2-way banks) ----
#pragma unroll
    for (int k = 0; k < (BB * ND) / NTHR; ++k) {
        const int idx = tid + k * NTHR;    // 4096 floats
        lds[XS_OFF + (idx >> 5) * STG_ROW + (idx & 31)] = Xg[idx];
    }

    // ---- Phase 1b: per-(ij, n) coefficients into LDS (each exactly once) ----
    // 64 ij * 32 n = 2048 pairs over 512 threads -> 4 each
#pragma unroll
    for (int k = 0; k < (TIJ * ND) / NTHR; ++k) {
        const int idx = tid + k * NTHR;
        const int ijl = idx >> 5;          // 0..63
        const int n   = idx & 31;
        const int ij  = ij0g + ijl;
        const int i   = ij >> 7;
        const int j   = ij & 127;
        const float s0  = S0[i * ND + n];
        const float s1  = S1[j * ND + n];
        const float mu0 = Mu0[i * ND + n];
        const float mu1 = Mu1[j * ND + n];
        const float Ds  = sqrtf(4.0f * s0 * s1 + EPS4);
        const float Cs  = 0.5f * (Ds - EPS2);
        const float Sigma = omt * omt * s0 + t * t * s1
                          + 2.0f * t * omt * Cs + EPS2 * t * omt;
        const float St  = (t * s1 + omt * Cs) - (omt * s0 + t * Cs) - EPS2 * t;
        const float Mut = omt * mu0 + t * mu1;
        const float v   = mu1 - mu0;
        const float invS = 1.0f / Sigma;
        const float Kf  = St * invS;
        const float cA  = -0.5f * invS;
        const float cB  = Mut * invS;
        lds[ijl * ROWF + n]      = cA;
        lds[ijl * ROWF + 32 + n] = cB;
        lds[ijl * ROWF + 64 + n] = Kf;
        lds[ijl * ROWF + 96 + n] = v - Kf * Mut;
        float cc = cA * Mut * Mut - 0.5f * __logf(Sigma);
        cc += __shfl_xor(cc, 1);
        cc += __shfl_xor(cc, 2);
        cc += __shfl_xor(cc, 4);
        cc += __shfl_xor(cc, 8);
        cc += __shfl_xor(cc, 16);
        if (n == 0) lds[CC_OFF + ijl] = cc;
    }
    if (tid < TIJ) lds[LAM_OFF + tid] = Lam[ij0g + tid];

    __syncthreads();

    // ---- Thread mapping: 2 b x 8 ij ----
    const int gij = tid & 7;      // ij-lane (lane bits 0-2)
    const int bl  = tid >> 3;     // 0..63 -> b in {bl, bl+64}

    // X rows -> registers (8-lane bcast groups, rows stride 36 -> bank offsets 4*bl)
    float x0[ND], x1[ND];
#pragma unroll
    for (int c = 0; c < 8; ++c) {
        const float4 v4 = *(const float4*)&lds[XS_OFF + bl * STG_ROW + 4 * c];
        const float4 w4 = *(const float4*)&lds[XS_OFF + (bl + 64) * STG_ROW + 4 * c];
        x0[4*c+0] = v4.x; x0[4*c+1] = v4.y; x0[4*c+2] = v4.z; x0[4*c+3] = v4.w;
        x1[4*c+0] = w4.x; x1[4*c+1] = w4.y; x1[4*c+2] = w4.z; x1[4*c+3] = w4.w;
    }

    float num0[ND], num1[ND];
#pragma unroll
    for (int n = 0; n < ND; ++n) { num0[n] = 0.0f; num1[n] = 0.0f; }
    float den0 = 0.0f, den1 = 0.0f;

    // ---- Phase 2: 8 iters, each: 1 coef row shared by 2 b ----
    // Wave reads 8 distinct rows (stride 132 fl -> bank offs 0,4,..,28): conflict-free
#pragma unroll
    for (int it = 0; it < TIJ / 8; ++it) {
        const int ijl = gij + (it << 3);
        const float* __restrict__ row = &lds[ijl * ROWF];
        const float cc0 = lds[CC_OFF + ijl];
        float la0 = cc0, lb0 = 0.0f;      // 4 independent logw chains
        float la1 = cc0, lb1 = 0.0f;
#pragma unroll
        for (int nc = 0; nc < 8; ++nc) {
            const float4 a  = *(const float4*)&row[nc * 4];
            const float4 bq = *(const float4*)&row[32 + nc * 4];
            la0 = fmaf(fmaf(a.x, x0[nc*4+0], bq.x), x0[nc*4+0], la0);
            lb0 = fmaf(fmaf(a.y, x0[nc*4+1], bq.y), x0[nc*4+1], lb0);
            la0 = fmaf(fmaf(a.z, x0[nc*4+2], bq.z), x0[nc*4+2], la0);
            lb0 = fmaf(fmaf(a.w, x0[nc*4+3], bq.w), x0[nc*4+3], lb0);
            la1 = fmaf(fmaf(a.x, x1[nc*4+0], bq.x), x1[nc*4+0], la1);
            lb1 = fmaf(fmaf(a.y, x1[nc*4+1], bq.y), x1[nc*4+1], lb1);
            la1 = fmaf(fmaf(a.z, x1[nc*4+2], bq.z), x1[nc*4+2], la1);
            lb1 = fmaf(fmaf(a.w, x1[nc*4+3], bq.w), x1[nc*4+3], lb1);
        }
        float lw0 = fminf(fmaxf(la0 + lb0, -50.0f), 50.0f);
        float lw1 = fminf(fmaxf(la1 + lb1, -50.0f), 50.0f);
        const float lam = lds[LAM_OFF + ijl];
        const float w0 = __expf(lw0) * lam;
        const float w1 = __expf(lw1) * lam;
        den0 += w0; den1 += w1;
#pragma unroll
        for (int nc = 0; nc < 8; ++nc) {
            const float4 kk = *(const float4*)&row[64 + nc * 4];
            const float4 kv = *(const float4*)&row[96 + nc * 4];
            num0[nc*4+0] = fmaf(w0, fmaf(kk.x, x0[nc*4+0], kv.x), num0[nc*4+0]);
            num0[nc*4+1] = fmaf(w0, fmaf(kk.y, x0[nc*4+1], kv.y), num0[nc*4+1]);
            num0[nc*4+2] = fmaf(w0, fmaf(kk.z, x0[nc*4+2], kv.z), num0[nc*4+2]);
            num0[nc*4+3] = fmaf(w0, fmaf(kk.w, x0[nc*4+3], kv.w), num0[nc*4+3]);
            num1[nc*4+0] = fmaf(w1, fmaf(kk.x, x1[nc*4+0], kv.x), num1[nc*4+0]);
            num1[nc*4+1] = fmaf(w1, fmaf(kk.y, x1[nc*4+1], kv.y), num1[nc*4+1]);
            num1[nc*4+2] = fmaf(w1, fmaf(kk.z, x1[nc*4+2], kv.z), num1[nc*4+2]);
            num1[nc*4+3] = fmaf(w1, fmaf(kk.w, x1[nc*4+3], kv.w), num1[nc*4+3]);
        }
    }

    // ---- Fold-reduce (reduce-scatter) across the 8 gij lanes ----
    // After 3 folds, lane gij holds summed columns [4*gij, 4*gij+4).
    // 28 shuffles per b (vs 96 for a full butterfly).
#pragma unroll
    for (int c = 0; c < 16; ++c) {         // mask 4: 32 -> 16 cols
        const float s0v = (gij & 4) ? num0[c] : num0[c + 16];
        const float s1v = (gij & 4) ? num1[c] : num1[c + 16];
        const float r0 = __shfl_xor(s0v, 4);
        const float r1 = __shfl_xor(s1v, 4);
        num0[c] = ((gij & 4) ? num0[c + 16] : num0[c]) + r0;
        num1[c] = ((gij & 4) ? num1[c + 16] : num1[c]) + r1;
    }
#pragma unroll
    for (int c = 0; c < 8; ++c) {          // mask 2: 16 -> 8 cols
        const float s0v = (gij & 2) ? num0[c] : num0[c + 8];
        const float s1v = (gij & 2) ? num1[c] : num1[c + 8];
        const float r0 = __shfl_xor(s0v, 2);
        const float r1 = __shfl_xor(s1v, 2);
        num0[c] = ((gij & 2) ? num0[c + 8] : num0[c]) + r0;
        num1[c] = ((gij & 2) ? num1[c + 8] : num1[c]) + r1;
    }
#pragma unroll
    for (int c = 0; c < 4; ++c) {          // mask 1: 8 -> 4 cols
        const float s0v = (gij & 1) ? num0[c] : num0[c + 4];
        const float s1v = (gij & 1) ? num1[c] : num1[c + 4];
        const float r0 = __shfl_xor(s0v, 1);
        const float r1 = __shfl_xor(s1v, 1);
        num0[c] = ((gij & 1) ? num0[c + 4] : num0[c]) + r0;
        num1[c] = ((gij & 1) ? num1[c + 4] : num1[c]) + r1;
    }

    den0 += __shfl_xor(den0, 1);
    den0 += __shfl_xor(den0, 2);
    den0 += __shfl_xor(den0, 4);
    den1 += __shfl_xor(den1, 1);
    den1 += __shfl_xor(den1, 2);
    den1 += __shfl_xor(den1, 4);

    // ---- Direct coalesced global store (no LDS stage, no extra barriers) ----
    // Wave-burst: 8 rows x 8 lanes x 16 B = 1 KB contiguous per inst.
    float* __restrict__ dstg = part + (size_t)blk * PART_STRIDE;
    *(float4*)(dstg + bl * 32 + gij * 4) =
        make_float4(num0[0], num0[1], num0[2], num0[3]);
    *(float4*)(dstg + (bl + 64) * 32 + gij * 4) =
        make_float4(num1[0], num1[1], num1[2], num1[3]);
    if (gij == 0) {
        dstg[DEN_OFF_P + bl]      = den0;
        dstg[DEN_OFF_P + bl + 64] = den1;
    }
}

// 256 blocks = (b, n-half). Thread (sg, n16): sums 16 slices; LDS combine.
__global__ __launch_bounds__(256) void gmm_reduce(
    const float* __restrict__ part,
    float* __restrict__ out)
{
    const int blk = blockIdx.x;            // 0..255
    const int b   = blk >> 1;
    const int nh  = blk & 1;
    const int tid = threadIdx.x;
    const int n16 = tid & 15;
    const int sg  = tid >> 4;              // 0..15 slice-groups
    const int n   = nh * 16 + n16;

    float num = 0.0f, den = 0.0f;
#pragma unroll
    for (int g = 0; g < 16; ++g) {
        const int s = sg + g * 16;         // slice 0..255
        const size_t base = (size_t)s * PART_STRIDE;
        num += part[base + b * 32 + n];
        den += part[base + DEN_OFF_P + b]; // same addr across n16 -> broadcast
    }

    __shared__ float red[16][18];
    red[sg][n16] = num;
    if (n16 == 0) red[sg][16] = den;
    __syncthreads();

    if (tid < 16) {
        float ns = 0.0f, ds = 0.0f;
#pragma unroll
        for (int k = 0; k < 16; ++k) {
            ns += red[k][tid];
            ds += red[k][16];
        }
        out[b * 32 + nh * 16 + tid] = ns / ds;
    }
}

extern "C" void kernel_launch(void* const* d_in, const int* in_sizes, int n_in,
                              void* d_out, int out_size, void* d_ws, size_t ws_size,
                              hipStream_t stream)
{
    const float* X   = (const float*)d_in[0];
    const float* t   = (const float*)d_in[1];
    const float* Mu0 = (const float*)d_in[2];
    const float* Mu1 = (const float*)d_in[3];
    const float* S0  = (const float*)d_in[4];
    const float* S1  = (const float*)d_in[5];
    const float* Lam = (const float*)d_in[6];
    float* out  = (float*)d_out;
    float* part = (float*)d_ws;             // NBLK * PART_STRIDE floats (4.3 MB)

    gmm_fused<<<NBLK, NTHR, 0, stream>>>(X, t, Mu0, Mu1, S0, S1, Lam, part);
    gmm_reduce<<<2 * BB, 256, 0, stream>>>(part, out);
}

// Round 2
// 81.371 us; speedup vs baseline: 1.0918x; 1.0918x over previous
//
#include <hip/hip_runtime.h>
#include <math.h>

// Problem constants
#define BB 128
#define ND 32
#define NIJ 16384
#define EPS2 0.25f
#define EPS4 0.0625f

// Tiling: 256 blocks x 64 ij, full batch per block.
// 1024 thr = 64 bl x 2 nh x 8 gij. Each thread: 2 b (bl, bl+64) x 8 ij x 16 n.
// Coef reads amortized over 2 b; n-split halves register file -> 16 waves/CU.
#define TIJ 64
#define NBLK (NIJ / TIJ)        // 256 (1/CU)
#define NTHR 1024
#define ROWF 132                // coef row: cA32|cB32|K32|KV32|pad4

// LDS layout (floats)
#define XS_OFF  8448            // X stage [128][36] (2-way banks max)
#define CC_OFF  13056
#define LAM_OFF 13120
#define LDS_FL  13184           // 52.7 KB
#define STG_ROW 36

// part layout per block (packed): num[128][32] @0, den[128] @4096
#define PART_STRIDE 4224
#define DEN_OFF_P 4096

__global__ __launch_bounds__(NTHR, 4) void gmm_fused(
    const float* __restrict__ Xg,
    const float* __restrict__ tptr,
    const float* __restrict__ Mu0, const float* __restrict__ Mu1,
    const float* __restrict__ S0,  const float* __restrict__ S1,
    const float* __restrict__ Lam,
    float* __restrict__ part)
{
    __shared__ __align__(16) float lds[LDS_FL];

    const int tid  = threadIdx.x;
    const int blk  = blockIdx.x;
    const int ij0g = blk * TIJ;
    const float t   = tptr[0];
    const float omt = 1.0f - t;

    // ---- Phase 1a: X full batch -> LDS stage [128][36], 1 float4/thread ----
    {
        const int r  = tid >> 3;           // 0..127
        const int c4 = (tid & 7) * 4;      // 0..28
        *(float4*)&lds[XS_OFF + r * STG_ROW + c4] =
            *(const float4*)&Xg[tid * 4];
    }

    // ---- Phase 1b: per-(ij, n) coefficients into LDS (each exactly once) ----
    // 64 ij * 32 n = 2048 pairs over 1024 threads -> 2 each
#pragma unroll
    for (int k = 0; k < (TIJ * ND) / NTHR; ++k) {
        const int idx = tid + k * NTHR;
        const int ijl = idx >> 5;          // 0..63
        const int n   = idx & 31;
        const int ij  = ij0g + ijl;
        const int i   = ij >> 7;
        const int j   = ij & 127;
        const float s0  = S0[i * ND + n];
        const float s1  = S1[j * ND + n];
        const float mu0 = Mu0[i * ND + n];
        const float mu1 = Mu1[j * ND + n];
        const float Ds  = sqrtf(4.0f * s0 * s1 + EPS4);
        const float Cs  = 0.5f * (Ds - EPS2);
        const float Sigma = omt * omt * s0 + t * t * s1
                          + 2.0f * t * omt * Cs + EPS2 * t * omt;
        const float St  = (t * s1 + omt * Cs) - (omt * s0 + t * Cs) - EPS2 * t;
        const float Mut = omt * mu0 + t * mu1;
        const float v   = mu1 - mu0;
        const float invS = 1.0f / Sigma;
        const float Kf  = St * invS;
        const float cA  = -0.5f * invS;
        const float cB  = Mut * invS;
        lds[ijl * ROWF + n]      = cA;
        lds[ijl * ROWF + 32 + n] = cB;
        lds[ijl * ROWF + 64 + n] = Kf;
        lds[ijl * ROWF + 96 + n] = v - Kf * Mut;
        float cc = cA * Mut * Mut - 0.5f * __logf(Sigma);
        cc += __shfl_xor(cc, 1);
        cc += __shfl_xor(cc, 2);
        cc += __shfl_xor(cc, 4);
        cc += __shfl_xor(cc, 8);
        cc += __shfl_xor(cc, 16);
        if (n == 0) lds[CC_OFF + ijl] = cc;
    }
    if (tid < TIJ) lds[LAM_OFF + tid] = Lam[ij0g + tid];

    __syncthreads();

    // ---- Thread mapping: 2 b x 8 ij x 16 n ----
    const int gij = tid & 7;          // lane bits 0-2: ij within group
    const int nh  = (tid >> 3) & 1;   // lane bit 3: n-half
    const int bl  = tid >> 4;         // 0..63 -> b in {bl, bl+64}
    const int n0  = nh * 16;

    // X half-rows -> registers (bcast groups; <=2-way banks)
    float x0[16], x1[16];
#pragma unroll
    for (int c = 0; c < 4; ++c) {
        const float4 v4 = *(const float4*)&lds[XS_OFF + bl * STG_ROW + n0 + 4 * c];
        const float4 w4 = *(const float4*)&lds[XS_OFF + (bl + 64) * STG_ROW + n0 + 4 * c];
        x0[4*c+0] = v4.x; x0[4*c+1] = v4.y; x0[4*c+2] = v4.z; x0[4*c+3] = v4.w;
        x1[4*c+0] = w4.x; x1[4*c+1] = w4.y; x1[4*c+2] = w4.z; x1[4*c+3] = w4.w;
    }

    float num0[16], num1[16];
#pragma unroll
    for (int n = 0; n < 16; ++n) { num0[n] = 0.0f; num1[n] = 0.0f; }
    float den0 = 0.0f, den1 = 0.0f;

    // ---- Phase 2: 8 iters; coef row shared by 2 b; n-half per thread ----
    // Wave reads 8 rows x 2 halves: bank groups pair up -> 2-way max (free)
#pragma unroll 2
    for (int it = 0; it < TIJ / 8; ++it) {
        const int ijl = gij + (it << 3);
        const float* __restrict__ row = &lds[ijl * ROWF + n0];
        float la0 = 0.0f, lb0 = 0.0f;     // 4 independent logw chains
        float la1 = 0.0f, lb1 = 0.0f;
#pragma unroll
        for (int nc = 0; nc < 4; ++nc) {
            const float4 a  = *(const float4*)&row[nc * 4];
            const float4 bq = *(const float4*)&row[32 + nc * 4];
            la0 = fmaf(fmaf(a.x, x0[nc*4+0], bq.x), x0[nc*4+0], la0);
            lb0 = fmaf(fmaf(a.y, x0[nc*4+1], bq.y), x0[nc*4+1], lb0);
            la0 = fmaf(fmaf(a.z, x0[nc*4+2], bq.z), x0[nc*4+2], la0);
            lb0 = fmaf(fmaf(a.w, x0[nc*4+3], bq.w), x0[nc*4+3], lb0);
            la1 = fmaf(fmaf(a.x, x1[nc*4+0], bq.x), x1[nc*4+0], la1);
            lb1 = fmaf(fmaf(a.y, x1[nc*4+1], bq.y), x1[nc*4+1], lb1);
            la1 = fmaf(fmaf(a.z, x1[nc*4+2], bq.z), x1[nc*4+2], la1);
            lb1 = fmaf(fmaf(a.w, x1[nc*4+3], bq.w), x1[nc*4+3], lb1);
        }
        // combine n-halves across lane bit 3 (both lanes end with full sum)
        float lw0 = la0 + lb0;  lw0 += __shfl_xor(lw0, 8);
        float lw1 = la1 + lb1;  lw1 += __shfl_xor(lw1, 8);
        const float cc0 = lds[CC_OFF + ijl];
        const float lam = lds[LAM_OFF + ijl];
        lw0 = fminf(fmaxf(lw0 + cc0, -50.0f), 50.0f);
        lw1 = fminf(fmaxf(lw1 + cc0, -50.0f), 50.0f);
        const float w0 = __expf(lw0) * lam;
        const float w1 = __expf(lw1) * lam;
        den0 += w0; den1 += w1;
#pragma unroll
        for (int nc = 0; nc < 4; ++nc) {
            const float4 kk = *(const float4*)&row[64 + nc * 4];
            const float4 kv = *(const float4*)&row[96 + nc * 4];
            num0[nc*4+0] = fmaf(w0, fmaf(kk.x, x0[nc*4+0], kv.x), num0[nc*4+0]);
            num0[nc*4+1] = fmaf(w0, fmaf(kk.y, x0[nc*4+1], kv.y), num0[nc*4+1]);
            num0[nc*4+2] = fmaf(w0, fmaf(kk.z, x0[nc*4+2], kv.z), num0[nc*4+2]);
            num0[nc*4+3] = fmaf(w0, fmaf(kk.w, x0[nc*4+3], kv.w), num0[nc*4+3]);
            num1[nc*4+0] = fmaf(w1, fmaf(kk.x, x1[nc*4+0], kv.x), num1[nc*4+0]);
            num1[nc*4+1] = fmaf(w1, fmaf(kk.y, x1[nc*4+1], kv.y), num1[nc*4+1]);
            num1[nc*4+2] = fmaf(w1, fmaf(kk.z, x1[nc*4+2], kv.z), num1[nc*4+2]);
            num1[nc*4+3] = fmaf(w1, fmaf(kk.w, x1[nc*4+3], kv.w), num1[nc*4+3]);
        }
    }

    // ---- Fold-reduce across the 8 gij lanes: 16 cols -> 2 cols/lane ----
#pragma unroll
    for (int c = 0; c < 8; ++c) {          // mask 4: 16 -> 8 cols
        const float s0v = (gij & 4) ? num0[c] : num0[c + 8];
        const float s1v = (gij & 4) ? num1[c] : num1[c + 8];
        const float r0 = __shfl_xor(s0v, 4);
        const float r1 = __shfl_xor(s1v, 4);
        num0[c] = ((gij & 4) ? num0[c + 8] : num0[c]) + r0;
        num1[c] = ((gij & 4) ? num1[c + 8] : num1[c]) + r1;
    }
#pragma unroll
    for (int c = 0; c < 4; ++c) {          // mask 2: 8 -> 4 cols
        const float s0v = (gij & 2) ? num0[c] : num0[c + 4];
        const float s1v = (gij & 2) ? num1[c] : num1[c + 4];
        const float r0 = __shfl_xor(s0v, 2);
        const float r1 = __shfl_xor(s1v, 2);
        num0[c] = ((gij & 2) ? num0[c + 4] : num0[c]) + r0;
        num1[c] = ((gij & 2) ? num1[c + 4] : num1[c]) + r1;
    }
#pragma unroll
    for (int c = 0; c < 2; ++c) {          // mask 1: 4 -> 2 cols
        const float s0v = (gij & 1) ? num0[c] : num0[c + 2];
        const float s1v = (gij & 1) ? num1[c] : num1[c + 2];
        const float r0 = __shfl_xor(s0v, 1);
        const float r1 = __shfl_xor(s1v, 1);
        num0[c] = ((gij & 1) ? num0[c + 2] : num0[c]) + r0;
        num1[c] = ((gij & 1) ? num1[c + 2] : num1[c]) + r1;
    }

    den0 += __shfl_xor(den0, 1);
    den0 += __shfl_xor(den0, 2);
    den0 += __shfl_xor(den0, 4);
    den1 += __shfl_xor(den1, 1);
    den1 += __shfl_xor(den1, 2);
    den1 += __shfl_xor(den1, 4);

    // ---- Direct coalesced global store (no LDS stage, no extra barriers) ----
    // Lane gij holds cols {2*gij, 2*gij+1} of its nh-half: float2 stores,
    // wave covers 4 b x 32 cols = 512 B contiguous per store inst.
    float* __restrict__ dstg = part + (size_t)blk * PART_STRIDE;
    *(float2*)(dstg + bl * 32 + n0 + 2 * gij) =
        make_float2(num0[0], num0[1]);
    *(float2*)(dstg + (bl + 64) * 32 + n0 + 2 * gij) =
        make_float2(num1[0], num1[1]);
    if ((tid & 15) == 0) {
        dstg[DEN_OFF_P + bl]      = den0;
        dstg[DEN_OFF_P + bl + 64] = den1;
    }
}

// 256 blocks = (b, n-half). Thread (sg, n16): sums 16 slices; LDS combine.
__global__ __launch_bounds__(256) void gmm_reduce(
    const float* __restrict__ part,
    float* __restrict__ out)
{
    const int blk = blockIdx.x;            // 0..255
    const int b   = blk >> 1;
    const int nh  = blk & 1;
    const int tid = threadIdx.x;
    const int n16 = tid & 15;
    const int sg  = tid >> 4;              // 0..15 slice-groups
    const int n   = nh * 16 + n16;

    float num = 0.0f, den = 0.0f;
#pragma unroll
    for (int g = 0; g < 16; ++g) {
        const int s = sg + g * 16;         // slice 0..255
        const size_t base = (size_t)s * PART_STRIDE;
        num += part[base + b * 32 + n];
        den += part[base + DEN_OFF_P + b]; // same addr across n16 -> broadcast
    }

    __shared__ float red[16][18];
    red[sg][n16] = num;
    if (n16 == 0) red[sg][16] = den;
    __syncthreads();

    if (tid < 16) {
        float ns = 0.0f, ds = 0.0f;
#pragma unroll
        for (int k = 0; k < 16; ++k) {
            ns += red[k][tid];
            ds += red[k][16];
        }
        out[b * 32 + nh * 16 + tid] = ns / ds;
    }
}

extern "C" void kernel_launch(void* const* d_in, const int* in_sizes, int n_in,
                              void* d_out, int out_size, void* d_ws, size_t ws_size,
                              hipStream_t stream)
{
    const float* X   = (const float*)d_in[0];
    const float* t   = (const float*)d_in[1];
    const float* Mu0 = (const float*)d_in[2];
    const float* Mu1 = (const float*)d_in[3];
    const float* S0  = (const float*)d_in[4];
    const float* S1  = (const float*)d_in[5];
    const float* Lam = (const float*)d_in[6];
    float* out  = (float*)d_out;
    float* part = (float*)d_ws;             // NBLK * PART_STRIDE floats (4.3 MB)

    gmm_fused<<<NBLK, NTHR, 0, stream>>>(X, t, Mu0, Mu1, S0, S1, Lam, part);
    gmm_reduce<<<2 * BB, 256, 0, stream>>>(part, out);
}